// Round 9
// baseline (676.377 us; speedup 1.0000x reference)
//
#include <hip/hip_runtime.h>
#include <math.h>

typedef __bf16 bf16_t;
typedef bf16_t bf16x8 __attribute__((ext_vector_type(8)));
typedef float  floatx4 __attribute__((ext_vector_type(4)));

constexpr int N_SEQ = 4096, BSZ = 4, CIN = 384, CDSSP = 64, CHID = 128, NBLK = 4;
constexpr int NTOK = BSZ * N_SEQ;                       // 16384
constexpr int TOK_PER_WAVE  = 16;
constexpr int MLP_BLOCKS  = NTOK / TOK_PER_WAVE;        // 1024 single-wave blocks

// ================= d_ws layout (16-byte units; 1 unit = 8 bf16) =================
// B-image: per kg-chunk 1024 units = [hi: nt*64+lane (512u)] || [lo: 512u].
//   input seq: 26 chunks (kg 0..11 = W_in, 12..23 = W_init, 24..25 = W_dssp)
//   hidden:    32 chunks = (rb*2+which)*4 + kg,  which 0=W1 1=W2
// A-image: relu'd inputs pre-split hi/lo in per-32-token-group frag order:
//   hi unit = A_HI + w*3328 + kg*128 + mt*64 + lane   (w=tokgrp/32, kg 0..25)
//   lo unit = same + A_UNITS
constexpr int U_HID   = 26624;             // 26*1024
constexpr int A_HI_U  = 59392;
constexpr int A_UNITS = 1703936;           // 512 * 3328
constexpr int A_LO_U  = A_HI_U + A_UNITS;
constexpr int WS_END_U = A_LO_U + A_UNITS; // 55.5 MB
constexpr int BAND_OFF = WS_END_U * 4;     // float index for band arrays
constexpr int PREP_B_THREADS = 29696;
constexpr int PREP_A_THREADS = A_UNITS;

__device__ __forceinline__ float softplus_f(float x) {
    return fmaxf(x, 0.f) + log1pf(expf(-fabsf(x)));
}
__device__ __forceinline__ unsigned short bf16_bits(bf16_t h) {
    union { bf16_t b; unsigned short u; } c; c.b = h; return c.u;
}
__device__ __forceinline__ bf16_t bits_bf16(unsigned int u) {
    union { unsigned short u; bf16_t b; } c; c.u = (unsigned short)u; return c.b;
}
__device__ __forceinline__ floatx4 mfma16(bf16x8 a, bf16x8 b, floatx4 c) {
    return __builtin_amdgcn_mfma_f32_16x16x32_bf16(a, b, c, 0, 0, 0);
}

// ---- prep: build B-image (split weights) and A-image (relu+split inputs) ----
__global__ __launch_bounds__(256) void prep_kernel(
    const float* __restrict__ s, const float* __restrict__ s_init,
    const float* __restrict__ dssp,
    const float* __restrict__ Win, const float* __restrict__ Winit,
    const float* __restrict__ Wd,  const float* __restrict__ W1,
    const float* __restrict__ W2,  bf16_t* __restrict__ wsb)
{
    const int g = (int)blockIdx.x * 256 + (int)threadIdx.x;
    if (g < PREP_B_THREADS) {
        const int c = g >> 9, r = g & 511;
        const int nt = r >> 6, lane = r & 63, col = lane & 15, q = lane >> 4;
        const int j = nt * 16 + col;
        const float* W; int C, kgl;
        if (c < 12)      { W = Win;   C = CIN;   kgl = c; }
        else if (c < 24) { W = Winit; C = CIN;   kgl = c - 12; }
        else if (c < 26) { W = Wd;    C = CDSSP; kgl = c - 24; }
        else {
            const int hc = c - 26, m = hc >> 2;
            W = (m & 1) ? W2 : W1;
            W += (size_t)(m >> 1) * CHID * CHID;
            C = CHID; kgl = hc & 3;
        }
        const float* sp = W + (size_t)j * C + (kgl * 4 + q) * 8;
        const float4 a = *(const float4*)sp;
        const float4 b = *(const float4*)(sp + 4);
        const float xs[8] = { a.x, a.y, a.z, a.w, b.x, b.y, b.z, b.w };
        bf16x8 vh, vl;
        #pragma unroll
        for (int i = 0; i < 8; ++i) {
            const float x = xs[i];
            const bf16_t h = (bf16_t)x;
            vh[i] = h; vl[i] = (bf16_t)(x - (float)h);
        }
        *(bf16x8*)(wsb + ((size_t)c * 1024 + r) * 8)       = vh;
        *(bf16x8*)(wsb + ((size_t)c * 1024 + 512 + r) * 8) = vl;
    } else {
        const int t2 = g - PREP_B_THREADS;               // 0 .. A_UNITS-1
        const int w  = t2 / 3328;
        const int r  = t2 - w * 3328;
        const int kg = r >> 7, r2 = r & 127;
        const int mt = r2 >> 6, lane = r2 & 63, col = lane & 15, q = lane >> 4;
        const int token = w * 32 + mt * 16 + col;
        const float* src; int C, kgl;
        if (kg < 12)      { src = s;      C = CIN;   kgl = kg; }
        else if (kg < 24) { src = s_init; C = CIN;   kgl = kg - 12; }
        else              { src = dssp;   C = CDSSP; kgl = kg - 24; }
        const float* sp = src + (size_t)token * C + kgl * 32 + q * 8;
        const float4 a = *(const float4*)sp;
        const float4 b = *(const float4*)(sp + 4);
        const float xs[8] = { a.x, a.y, a.z, a.w, b.x, b.y, b.z, b.w };
        bf16x8 vh, vl;
        #pragma unroll
        for (int i = 0; i < 8; ++i) {
            const float x = fmaxf(xs[i], 0.f);
            const bf16_t h = (bf16_t)x;
            vh[i] = h; vl[i] = (bf16_t)(x - (float)h);
        }
        *(bf16x8*)(wsb + ((size_t)A_HI_U + t2) * 8) = vh;
        *(bf16x8*)(wsb + ((size_t)A_LO_U + t2) * 8) = vl;
    }
}

// ---- B-frag register set ----
struct BF { bf16x8 h[8]; bf16x8 l[8]; };

__device__ __forceinline__ void loadB(const bf16_t* __restrict__ img, int kg, int lane, BF& B) {
    const bf16_t* cb = img + (size_t)(kg * 1024 + lane) * 8;
    #pragma unroll
    for (int nt = 0; nt < 8; ++nt) {
        B.h[nt] = *(const bf16x8*)(cb + (size_t)(nt * 64) * 8);
        B.l[nt] = *(const bf16x8*)(cb + (size_t)(512 + nt * 64) * 8);
    }
}

// term-major: 8 independent MFMAs between dependent uses; per-acc order hh,lh,hl
__device__ __forceinline__ void mfma_step(const bf16x8 ahi, const bf16x8 alo,
                                          const BF& B, floatx4 (&ac)[8]) {
    #pragma unroll
    for (int nt = 0; nt < 8; ++nt) ac[nt] = mfma16(ahi, B.h[nt], ac[nt]);
    #pragma unroll
    for (int nt = 0; nt < 8; ++nt) ac[nt] = mfma16(alo, B.h[nt], ac[nt]);
    #pragma unroll
    for (int nt = 0; nt < 8; ++nt) ac[nt] = mfma16(ahi, B.l[nt], ac[nt]);
}

// A-frags from the wave-private Act plane (packed hi|lo per k)
__device__ __forceinline__ void ldsA(const uint32_t (*A)[132], int kg, int col, int q,
                                     bf16x8& ahi, bf16x8& alo) {
    const uint32_t* p = &A[col][kg * 32 + q * 8];
    const uint4 u0 = *(const uint4*)p;
    const uint4 u1 = *(const uint4*)(p + 4);
    const uint32_t uu[8] = { u0.x, u0.y, u0.z, u0.w, u1.x, u1.y, u1.z, u1.w };
    union { uint32_t u[4]; bf16x8 v; } ch, cl;
    #pragma unroll
    for (int i = 0; i < 4; ++i) {
        ch.u[i] = (uu[2*i] & 0xffffu) | (uu[2*i+1] << 16);
        cl.u[i] = (uu[2*i] >> 16) | (uu[2*i+1] & 0xffff0000u);
    }
    ahi = ch.v; alo = cl.v;
}

// hidden matmul (K=128), rolled kg loop, B double-buffered
__device__ __forceinline__ void hidden_pass(const uint32_t (*A)[132],
    const bf16_t* __restrict__ img, int lane, int col, int q, floatx4 (&ac)[8])
{
    BF B[2];
    loadB(img, 0, lane, B[0]);
    #pragma unroll 1
    for (int kg = 0; kg < 4; ++kg) {
        if (kg < 3) loadB(img, kg + 1, lane, B[(kg + 1) & 1]);
        bf16x8 ahi, alo;
        ldsA(A, kg, col, q, ahi, alo);
        mfma_step(ahi, alo, B[kg & 1], ac);
    }
}

// ---- MLP: 1024 single-wave blocks, 16 tokens each -> 4 waves/CU, all SIMDs ----
__global__ __launch_bounds__(64) void mlp_kernel(
    const float* __restrict__ b_in, const float* __restrict__ b_init,
    const float* __restrict__ b_dssp,
    const float* __restrict__ b1, const float* __restrict__ b2,
    const float* __restrict__ W_out, const float* __restrict__ b_out,
    const float* __restrict__ W_mult, const float* __restrict__ b_mult,
    const bf16_t* __restrict__ wsb, float* __restrict__ band)
{
    __shared__ uint32_t A[16][132];                 // 8.4 KB, wave-private act plane

    const int lane = (int)threadIdx.x;              // 0..63
    const int col  = lane & 15;
    const int q    = lane >> 4;
    const int blk  = (int)blockIdx.x;               // 0..1023
    const int w    = blk >> 1;                      // 32-token group in A-image
    const int mt   = blk & 1;                       // which 16-token half
    const int t0w  = blk * TOK_PER_WAVE;

    // h accumulators (C-frag layout): hacc[nt] -> token q*4+r, ch nt*16+col
    floatx4 hacc[8];
    #pragma unroll
    for (int nt = 0; nt < 8; ++nt) {
        const int j = nt * 16 + col;
        const float b = b_in[j] + b_init[j] + b_dssp[j];
        floatx4 v = { b, b, b, b };
        hacc[nt] = v;
    }

    // ---- input layer: one rolled loop, A+B both coalesced from global images ----
    {
        const bf16_t* ab = wsb +
            ((size_t)A_HI_U + (size_t)w * 3328 + mt * 64 + lane) * 8;
        auto loadA = [&](int kg, bf16x8& ahi, bf16x8& alo) {
            const bf16_t* p = ab + (size_t)(kg * 128) * 8;
            ahi = *(const bf16x8*)p;
            alo = *(const bf16x8*)(p + (size_t)A_UNITS * 8);
        };
        BF B[2];
        bf16x8 AH[2], AL[2];
        loadA(0, AH[0], AL[0]);
        loadB(wsb, 0, lane, B[0]);
        #pragma unroll 1
        for (int kg = 0; kg < 26; ++kg) {
            const int cur = kg & 1, nxt = cur ^ 1;
            if (kg + 1 < 26) {
                loadA(kg + 1, AH[nxt], AL[nxt]);
                loadB(wsb, kg + 1, lane, B[nxt]);
            }
            mfma_step(AH[cur], AL[cur], B[cur], hacc);
        }
    }

    // C-layout -> packed relu act plane (16 tokens)
    auto exchange = [&](floatx4 (&ac)[8]) {
        #pragma unroll
        for (int nt = 0; nt < 8; ++nt)
        #pragma unroll
        for (int r = 0; r < 4; ++r) {
            const float x = fmaxf(ac[nt][r], 0.f);
            const bf16_t h = (bf16_t)x;
            const bf16_t l = (bf16_t)(x - (float)h);
            A[q * 4 + r][nt * 16 + col] =
                (uint32_t)bf16_bits(h) | ((uint32_t)bf16_bits(l) << 16);
        }
        __syncthreads();   // 1-wave barrier: orders DS write->read
    };

    #pragma unroll 1
    for (int rb = 0; rb < NBLK; ++rb) {
        exchange(hacc);                               // A = relu(h)
        floatx4 vacc[8];
        #pragma unroll
        for (int nt = 0; nt < 8; ++nt) {
            const float b = b1[rb * CHID + nt * 16 + col];
            floatx4 v = { b, b, b, b };
            vacc[nt] = v;
        }
        hidden_pass(A, wsb + (size_t)(U_HID + (rb * 2 + 0) * 4096) * 8, lane, col, q, vacc);

        exchange(vacc);                               // A = relu(v)
        #pragma unroll
        for (int nt = 0; nt < 8; ++nt) {
            const float b = b2[rb * CHID + nt * 16 + col];
            floatx4 tt = hacc[nt];
            tt[0] += b; tt[1] += b; tt[2] += b; tt[3] += b;
            hacc[nt] = tt;
        }
        hidden_pass(A, wsb + (size_t)(U_HID + (rb * 2 + 1) * 4096) * 8, lane, col, q, hacc);
    }
    exchange(hacc);                                   // A = relu(h_final)

    // ---- head: each lane group (q) computes 2 dots for its token t ----
    // grp0: o0 & o4; grp1: o1 & o5(=a); grp2: o2 & o6(=b); grp3: o3
    const int t   = col;
    const int grp = q;
    const float* wA = W_out + (size_t)grp * CHID;
    float dA = b_out[grp], dB;
    const float* wB;
    if (grp == 0)      { wB = W_out + 4 * CHID; dB = b_out[4]; }
    else if (grp == 1) { wB = W_mult;           dB = b_mult[0]; }
    else if (grp == 2) { wB = W_mult + CHID;    dB = b_mult[1]; }
    else               { wB = W_out;            dB = 0.f; }
    #pragma unroll 1
    for (int k = 0; k < CHID; ++k) {
        const uint32_t pk = A[t][k];
        const float x = (float)bits_bf16(pk & 0xffffu) + (float)bits_bf16(pk >> 16);
        dA = fmaf(x, wA[k], dA);
        dB = fmaf(x, wB[k], dB);
    }
    const float av = __shfl(dB, 16 + t);   // grp1's W_mult[0] dot for token t
    const float bv = __shfl(dB, 32 + t);   // grp2's W_mult[1] dot for token t
    const int g = t0w + t;
    if (grp == 0) {
        band[g]          = softplus_f(dA) * softplus_f(av) + softplus_f(bv);
        band[4*NTOK + g] = dB;   // c4
    } else if (grp == 1) {
        band[NTOK + g]   = dA;   // c1
    } else if (grp == 2) {
        band[2*NTOK + g] = dA;   // c2
    } else {
        band[3*NTOK + g] = dA;   // c3
    }
}

// ---- pure streaming zero-fill: branch-free nontemporal stores (R6-proven) ----
__global__ __launch_bounds__(256) void zero_fill(float* __restrict__ out)
{
    floatx4* dst = (floatx4*)(out + (size_t)blockIdx.x * 32768);   // 128 KB/block
    const floatx4 z = { 0.f, 0.f, 0.f, 0.f };
    #pragma unroll 1
    for (int i = (int)threadIdx.x; i < 8192; i += 256)
        __builtin_nontemporal_store(z, dst + i);
}

// ---- patch the three diagonals (each cell fully overwritten; no RMW) ----
__global__ __launch_bounds__(256) void band_patch(
    const float* __restrict__ band, const float* __restrict__ p_sm,
    float* __restrict__ out)
{
    const int g = (int)blockIdx.x * 256 + (int)threadIdx.x;   // 0..16383
    const int b = g >> 12;
    const int i = g & (N_SEQ - 1);
    const float sm = *p_sm;
    const size_t rowbase = (size_t)b * N_SEQ * N_SEQ + (size_t)i * N_SEQ;
    out[rowbase + i] = sm * band[g];
    if (i >= 1) out[rowbase + i - 1] = sm * (band[NTOK + g] + band[3*NTOK + g - 1]);
    if (i >= 2) out[rowbase + i - 2] = sm * (band[2*NTOK + g] + band[4*NTOK + g - 2]);
}

extern "C" void kernel_launch(void* const* d_in, const int* in_sizes, int n_in,
                              void* d_out, int out_size, void* d_ws, size_t ws_size,
                              hipStream_t stream)
{
    const float* s      = (const float*)d_in[0];
    const float* s_init = (const float*)d_in[1];
    const float* dssp   = (const float*)d_in[2];
    const float* W_in   = (const float*)d_in[3];
    const float* b_in   = (const float*)d_in[4];
    const float* W_init = (const float*)d_in[5];
    const float* b_initp= (const float*)d_in[6];
    const float* W_dssp = (const float*)d_in[7];
    const float* b_dsspp= (const float*)d_in[8];
    const float* W1     = (const float*)d_in[9];
    const float* b1     = (const float*)d_in[10];
    const float* W2     = (const float*)d_in[11];
    const float* b2     = (const float*)d_in[12];
    const float* W_out  = (const float*)d_in[13];
    const float* b_out  = (const float*)d_in[14];
    const float* W_mult = (const float*)d_in[15];
    const float* b_mult = (const float*)d_in[16];
    const float* sm     = (const float*)d_in[17];
    bf16_t* wsb  = (bf16_t*)d_ws;
    float*  band = (float*)d_ws + BAND_OFF;
    float*  out  = (float*)d_out;

    const int prep_blocks = (PREP_B_THREADS + PREP_A_THREADS) / 256;   // 6772
    prep_kernel<<<prep_blocks, 256, 0, stream>>>(
        s, s_init, dssp, W_in, W_init, W_dssp, W1, W2, wsb);

    mlp_kernel<<<MLP_BLOCKS, 64, 0, stream>>>(
        b_in, b_initp, b_dsspp, b1, b2,
        W_out, b_out, W_mult, b_mult, (const bf16_t*)wsb, band);

    zero_fill<<<2048, 256, 0, stream>>>(out);

    band_patch<<<NTOK / 256, 256, 0, stream>>>(band, sm, out);
}

// Round 10
// 408.216 us; speedup vs baseline: 1.6569x; 1.6569x over previous
//
#include <hip/hip_runtime.h>
#include <math.h>

typedef __bf16 bf16_t;
typedef bf16_t bf16x8 __attribute__((ext_vector_type(8)));
typedef float  floatx4 __attribute__((ext_vector_type(4)));

constexpr int N_SEQ = 4096, BSZ = 4, CIN = 384, CDSSP = 64, CHID = 128, NBLK = 4;
constexpr int NTOK = BSZ * N_SEQ;                       // 16384
constexpr int TOK_PER_WAVE  = 16;
constexpr int MLP_BLOCKS  = NTOK / TOK_PER_WAVE;        // 1024 single-wave blocks

// ================= d_ws layout (16-byte units; 1 unit = 8 bf16) =================
// B-image: per kg-chunk 1024 units = [hi: nt*64+lane (512u)] || [lo: 512u].
//   input seq: 26 chunks (kg 0..11 = W_in, 12..23 = W_init, 24..25 = W_dssp)
//   hidden:    32 chunks = (rb*2+which)*4 + kg,  which 0=W1 1=W2
// A-image: relu'd inputs pre-split hi/lo in per-32-token-group frag order:
//   hi unit = A_HI + w*3328 + kg*128 + mt*64 + lane   (w=tokgrp/32, kg 0..25)
//   lo unit = same + A_UNITS
constexpr int U_HID   = 26624;             // 26*1024
constexpr int A_HI_U  = 59392;
constexpr int A_UNITS = 1703936;           // 512 * 3328
constexpr int A_LO_U  = A_HI_U + A_UNITS;
constexpr int WS_END_U = A_LO_U + A_UNITS; // 55.5 MB
constexpr int BAND_OFF = WS_END_U * 4;     // float index for band arrays
constexpr int PREP_B_THREADS = 29696;
constexpr int PREP_A_THREADS = A_UNITS;

__device__ __forceinline__ float softplus_f(float x) {
    return fmaxf(x, 0.f) + log1pf(expf(-fabsf(x)));
}
__device__ __forceinline__ unsigned short bf16_bits(bf16_t h) {
    union { bf16_t b; unsigned short u; } c; c.b = h; return c.u;
}
__device__ __forceinline__ bf16_t bits_bf16(unsigned int u) {
    union { unsigned short u; bf16_t b; } c; c.u = (unsigned short)u; return c.b;
}
__device__ __forceinline__ floatx4 mfma16(bf16x8 a, bf16x8 b, floatx4 c) {
    return __builtin_amdgcn_mfma_f32_16x16x32_bf16(a, b, c, 0, 0, 0);
}

// ---- prep: build B-image (split weights) and A-image (relu+split inputs) ----
__global__ __launch_bounds__(256) void prep_kernel(
    const float* __restrict__ s, const float* __restrict__ s_init,
    const float* __restrict__ dssp,
    const float* __restrict__ Win, const float* __restrict__ Winit,
    const float* __restrict__ Wd,  const float* __restrict__ W1,
    const float* __restrict__ W2,  bf16_t* __restrict__ wsb)
{
    const int g = (int)blockIdx.x * 256 + (int)threadIdx.x;
    if (g < PREP_B_THREADS) {
        const int c = g >> 9, r = g & 511;
        const int nt = r >> 6, lane = r & 63, col = lane & 15, q = lane >> 4;
        const int j = nt * 16 + col;
        const float* W; int C, kgl;
        if (c < 12)      { W = Win;   C = CIN;   kgl = c; }
        else if (c < 24) { W = Winit; C = CIN;   kgl = c - 12; }
        else if (c < 26) { W = Wd;    C = CDSSP; kgl = c - 24; }
        else {
            const int hc = c - 26, m = hc >> 2;
            W = (m & 1) ? W2 : W1;
            W += (size_t)(m >> 1) * CHID * CHID;
            C = CHID; kgl = hc & 3;
        }
        const float* sp = W + (size_t)j * C + (kgl * 4 + q) * 8;
        const float4 a = *(const float4*)sp;
        const float4 b = *(const float4*)(sp + 4);
        const float xs[8] = { a.x, a.y, a.z, a.w, b.x, b.y, b.z, b.w };
        bf16x8 vh, vl;
        #pragma unroll
        for (int i = 0; i < 8; ++i) {
            const float x = xs[i];
            const bf16_t h = (bf16_t)x;
            vh[i] = h; vl[i] = (bf16_t)(x - (float)h);
        }
        *(bf16x8*)(wsb + ((size_t)c * 1024 + r) * 8)       = vh;
        *(bf16x8*)(wsb + ((size_t)c * 1024 + 512 + r) * 8) = vl;
    } else {
        const int t2 = g - PREP_B_THREADS;               // 0 .. A_UNITS-1
        const int w  = t2 / 3328;
        const int r  = t2 - w * 3328;
        const int kg = r >> 7, r2 = r & 127;
        const int mt = r2 >> 6, lane = r2 & 63, col = lane & 15, q = lane >> 4;
        const int token = w * 32 + mt * 16 + col;
        const float* src; int C, kgl;
        if (kg < 12)      { src = s;      C = CIN;   kgl = kg; }
        else if (kg < 24) { src = s_init; C = CIN;   kgl = kg - 12; }
        else              { src = dssp;   C = CDSSP; kgl = kg - 24; }
        const float* sp = src + (size_t)token * C + kgl * 32 + q * 8;
        const float4 a = *(const float4*)sp;
        const float4 b = *(const float4*)(sp + 4);
        const float xs[8] = { a.x, a.y, a.z, a.w, b.x, b.y, b.z, b.w };
        bf16x8 vh, vl;
        #pragma unroll
        for (int i = 0; i < 8; ++i) {
            const float x = fmaxf(xs[i], 0.f);
            const bf16_t h = (bf16_t)x;
            vh[i] = h; vl[i] = (bf16_t)(x - (float)h);
        }
        *(bf16x8*)(wsb + ((size_t)A_HI_U + t2) * 8) = vh;
        *(bf16x8*)(wsb + ((size_t)A_LO_U + t2) * 8) = vl;
    }
}

// ---- B-plane loads: hi and lo halves, each 8 coalesced 1KB loads ----
__device__ __forceinline__ void loadBh(const bf16_t* __restrict__ img, int kg, int lane,
                                       bf16x8 (&Bh)[8]) {
    const bf16_t* cb = img + (size_t)(kg * 1024 + lane) * 8;
    #pragma unroll
    for (int nt = 0; nt < 8; ++nt)
        Bh[nt] = *(const bf16x8*)(cb + (size_t)(nt * 64) * 8);
}
__device__ __forceinline__ void loadBl(const bf16_t* __restrict__ img, int kg, int lane,
                                       bf16x8 (&Bl)[8]) {
    const bf16_t* cb = img + (size_t)(kg * 1024 + 512 + lane) * 8;
    #pragma unroll
    for (int nt = 0; nt < 8; ++nt)
        Bl[nt] = *(const bf16x8*)(cb + (size_t)(nt * 64) * 8);
}

// term-major; per-kg order: hh(nt0..7), lh(nt0..7), hl(nt0..7)  (bit-identical)
__device__ __forceinline__ void mfma_hh_lh(bf16x8 ahi, bf16x8 alo,
                                           const bf16x8 (&Bh)[8], floatx4 (&ac)[8]) {
    #pragma unroll
    for (int nt = 0; nt < 8; ++nt) ac[nt] = mfma16(ahi, Bh[nt], ac[nt]);
    #pragma unroll
    for (int nt = 0; nt < 8; ++nt) ac[nt] = mfma16(alo, Bh[nt], ac[nt]);
}
__device__ __forceinline__ void mfma_hl(bf16x8 ahi, const bf16x8 (&Bl)[8], floatx4 (&ac)[8]) {
    #pragma unroll
    for (int nt = 0; nt < 8; ++nt) ac[nt] = mfma16(ahi, Bl[nt], ac[nt]);
}

// A-frags from the wave-private Act plane (packed hi|lo per k)
__device__ __forceinline__ void ldsA(const uint32_t (*A)[132], int kg, int col, int q,
                                     bf16x8& ahi, bf16x8& alo) {
    const uint32_t* p = &A[col][kg * 32 + q * 8];
    const uint4 u0 = *(const uint4*)p;
    const uint4 u1 = *(const uint4*)(p + 4);
    const uint32_t uu[8] = { u0.x, u0.y, u0.z, u0.w, u1.x, u1.y, u1.z, u1.w };
    union { uint32_t u[4]; bf16x8 v; } ch, cl;
    #pragma unroll
    for (int i = 0; i < 4; ++i) {
        ch.u[i] = (uu[2*i] & 0xffffu) | (uu[2*i+1] << 16);
        cl.u[i] = (uu[2*i] >> 16) | (uu[2*i+1] & 0xffff0000u);
    }
    ahi = ch.v; alo = cl.v;
}

// hidden matmul (K=128): Bh double-buffered, Bl just-in-time, unroll-2
__device__ __forceinline__ void hidden_pass(const uint32_t (*A)[132],
    const bf16_t* __restrict__ img, int lane, int col, int q, floatx4 (&ac)[8])
{
    bf16x8 Bh0[8], Bh1[8], Bl[8];
    bf16x8 ah0, al0, ah1, al1;
    loadBh(img, 0, lane, Bh0); ldsA(A, 0, col, q, ah0, al0);
    #pragma unroll 1
    for (int kg = 0; kg < 4; kg += 2) {
        loadBl(img, kg, lane, Bl);
        loadBh(img, kg + 1, lane, Bh1); ldsA(A, kg + 1, col, q, ah1, al1);
        mfma_hh_lh(ah0, al0, Bh0, ac);
        mfma_hl(ah0, Bl, ac);
        loadBl(img, kg + 1, lane, Bl);
        if (kg + 2 < 4) { loadBh(img, kg + 2, lane, Bh0); ldsA(A, kg + 2, col, q, ah0, al0); }
        mfma_hh_lh(ah1, al1, Bh1, ac);
        mfma_hl(ah1, Bl, ac);
    }
}

// ---- MLP: 1024 single-wave blocks, 16 tokens each -> 4 waves/CU, all SIMDs ----
// launch_bounds (64,2): 256-VGPR budget; live set ~196 regs -> no scratch spill.
__global__ __launch_bounds__(64, 2) void mlp_kernel(
    const float* __restrict__ b_in, const float* __restrict__ b_init,
    const float* __restrict__ b_dssp,
    const float* __restrict__ b1, const float* __restrict__ b2,
    const float* __restrict__ W_out, const float* __restrict__ b_out,
    const float* __restrict__ W_mult, const float* __restrict__ b_mult,
    const bf16_t* __restrict__ wsb, float* __restrict__ band)
{
    __shared__ uint32_t A[16][132];                 // 8.4 KB, wave-private act plane

    const int lane = (int)threadIdx.x;              // 0..63
    const int col  = lane & 15;
    const int q    = lane >> 4;
    const int blk  = (int)blockIdx.x;               // 0..1023
    const int w    = blk >> 1;                      // 32-token group in A-image
    const int mt   = blk & 1;                       // which 16-token half
    const int t0w  = blk * TOK_PER_WAVE;

    // h accumulators (C-frag layout): hacc[nt] -> token q*4+r, ch nt*16+col
    floatx4 hacc[8];
    #pragma unroll
    for (int nt = 0; nt < 8; ++nt) {
        const int j = nt * 16 + col;
        const float b = b_in[j] + b_init[j] + b_dssp[j];
        floatx4 v = { b, b, b, b };
        hacc[nt] = v;
    }

    // ---- input layer: A+B coalesced from global images, unroll-2 pipeline ----
    {
        const bf16_t* ab = wsb +
            ((size_t)A_HI_U + (size_t)w * 3328 + mt * 64 + lane) * 8;
        auto loadA = [&](int kg, bf16x8& ahi, bf16x8& alo) {
            const bf16_t* p = ab + (size_t)(kg * 128) * 8;
            ahi = *(const bf16x8*)p;
            alo = *(const bf16x8*)(p + (size_t)A_UNITS * 8);
        };
        bf16x8 Bh0[8], Bh1[8], Bl[8];
        bf16x8 ah0, al0, ah1, al1;
        loadBh(wsb, 0, lane, Bh0); loadA(0, ah0, al0);
        #pragma unroll 1
        for (int kg = 0; kg < 26; kg += 2) {
            loadBl(wsb, kg, lane, Bl);
            loadBh(wsb, kg + 1, lane, Bh1); loadA(kg + 1, ah1, al1);
            mfma_hh_lh(ah0, al0, Bh0, hacc);
            mfma_hl(ah0, Bl, hacc);
            loadBl(wsb, kg + 1, lane, Bl);
            if (kg + 2 < 26) { loadBh(wsb, kg + 2, lane, Bh0); loadA(kg + 2, ah0, al0); }
            mfma_hh_lh(ah1, al1, Bh1, hacc);
            mfma_hl(ah1, Bl, hacc);
        }
    }

    // C-layout -> packed relu act plane (16 tokens)
    auto exchange = [&](floatx4 (&ac)[8]) {
        #pragma unroll
        for (int nt = 0; nt < 8; ++nt)
        #pragma unroll
        for (int r = 0; r < 4; ++r) {
            const float x = fmaxf(ac[nt][r], 0.f);
            const bf16_t h = (bf16_t)x;
            const bf16_t l = (bf16_t)(x - (float)h);
            A[q * 4 + r][nt * 16 + col] =
                (uint32_t)bf16_bits(h) | ((uint32_t)bf16_bits(l) << 16);
        }
        __syncthreads();   // 1-wave barrier: orders DS write->read
    };

    #pragma unroll 1
    for (int rb = 0; rb < NBLK; ++rb) {
        exchange(hacc);                               // A = relu(h)
        floatx4 vacc[8];
        #pragma unroll
        for (int nt = 0; nt < 8; ++nt) {
            const float b = b1[rb * CHID + nt * 16 + col];
            floatx4 v = { b, b, b, b };
            vacc[nt] = v;
        }
        hidden_pass(A, wsb + (size_t)(U_HID + (rb * 2 + 0) * 4096) * 8, lane, col, q, vacc);

        exchange(vacc);                               // A = relu(v)
        #pragma unroll
        for (int nt = 0; nt < 8; ++nt) {
            const float b = b2[rb * CHID + nt * 16 + col];
            floatx4 tt = hacc[nt];
            tt[0] += b; tt[1] += b; tt[2] += b; tt[3] += b;
            hacc[nt] = tt;
        }
        hidden_pass(A, wsb + (size_t)(U_HID + (rb * 2 + 1) * 4096) * 8, lane, col, q, hacc);
    }
    exchange(hacc);                                   // A = relu(h_final)

    // ---- head: each lane group (q) computes 2 dots for its token t ----
    // grp0: o0 & o4; grp1: o1 & o5(=a); grp2: o2 & o6(=b); grp3: o3
    const int t   = col;
    const int grp = q;
    const float* wA = W_out + (size_t)grp * CHID;
    float dA = b_out[grp], dB;
    const float* wB;
    if (grp == 0)      { wB = W_out + 4 * CHID; dB = b_out[4]; }
    else if (grp == 1) { wB = W_mult;           dB = b_mult[0]; }
    else if (grp == 2) { wB = W_mult + CHID;    dB = b_mult[1]; }
    else               { wB = W_out;            dB = 0.f; }
    #pragma unroll 1
    for (int k = 0; k < CHID; ++k) {
        const uint32_t pk = A[t][k];
        const float x = (float)bits_bf16(pk & 0xffffu) + (float)bits_bf16(pk >> 16);
        dA = fmaf(x, wA[k], dA);
        dB = fmaf(x, wB[k], dB);
    }
    const float av = __shfl(dB, 16 + t);   // grp1's W_mult[0] dot for token t
    const float bv = __shfl(dB, 32 + t);   // grp2's W_mult[1] dot for token t
    const int g = t0w + t;
    if (grp == 0) {
        band[g]          = softplus_f(dA) * softplus_f(av) + softplus_f(bv);
        band[4*NTOK + g] = dB;   // c4
    } else if (grp == 1) {
        band[NTOK + g]   = dA;   // c1
    } else if (grp == 2) {
        band[2*NTOK + g] = dA;   // c2
    } else {
        band[3*NTOK + g] = dA;   // c3
    }
}

// ---- pure streaming zero-fill: branch-free nontemporal stores (R6-proven) ----
__global__ __launch_bounds__(256) void zero_fill(float* __restrict__ out)
{
    floatx4* dst = (floatx4*)(out + (size_t)blockIdx.x * 32768);   // 128 KB/block
    const floatx4 z = { 0.f, 0.f, 0.f, 0.f };
    #pragma unroll 1
    for (int i = (int)threadIdx.x; i < 8192; i += 256)
        __builtin_nontemporal_store(z, dst + i);
}

// ---- patch the three diagonals (each cell fully overwritten; no RMW) ----
__global__ __launch_bounds__(256) void band_patch(
    const float* __restrict__ band, const float* __restrict__ p_sm,
    float* __restrict__ out)
{
    const int g = (int)blockIdx.x * 256 + (int)threadIdx.x;   // 0..16383
    const int b = g >> 12;
    const int i = g & (N_SEQ - 1);
    const float sm = *p_sm;
    const size_t rowbase = (size_t)b * N_SEQ * N_SEQ + (size_t)i * N_SEQ;
    out[rowbase + i] = sm * band[g];
    if (i >= 1) out[rowbase + i - 1] = sm * (band[NTOK + g] + band[3*NTOK + g - 1]);
    if (i >= 2) out[rowbase + i - 2] = sm * (band[2*NTOK + g] + band[4*NTOK + g - 2]);
}

extern "C" void kernel_launch(void* const* d_in, const int* in_sizes, int n_in,
                              void* d_out, int out_size, void* d_ws, size_t ws_size,
                              hipStream_t stream)
{
    const float* s      = (const float*)d_in[0];
    const float* s_init = (const float*)d_in[1];
    const float* dssp   = (const float*)d_in[2];
    const float* W_in   = (const float*)d_in[3];
    const float* b_in   = (const float*)d_in[4];
    const float* W_init = (const float*)d_in[5];
    const float* b_initp= (const float*)d_in[6];
    const float* W_dssp = (const float*)d_in[7];
    const float* b_dsspp= (const float*)d_in[8];
    const float* W1     = (const float*)d_in[9];
    const float* b1     = (const float*)d_in[10];
    const float* W2     = (const float*)d_in[11];
    const float* b2     = (const float*)d_in[12];
    const float* W_out  = (const float*)d_in[13];
    const float* b_out  = (const float*)d_in[14];
    const float* W_mult = (const float*)d_in[15];
    const float* b_mult = (const float*)d_in[16];
    const float* sm     = (const float*)d_in[17];
    bf16_t* wsb  = (bf16_t*)d_ws;
    float*  band = (float*)d_ws + BAND_OFF;
    float*  out  = (float*)d_out;

    const int prep_blocks = (PREP_B_THREADS + PREP_A_THREADS) / 256;   // 6772
    prep_kernel<<<prep_blocks, 256, 0, stream>>>(
        s, s_init, dssp, W_in, W_init, W_dssp, W1, W2, wsb);

    mlp_kernel<<<MLP_BLOCKS, 64, 0, stream>>>(
        b_in, b_initp, b_dsspp, b1, b2,
        W_out, b_out, W_mult, b_mult, (const bf16_t*)wsb, band);

    zero_fill<<<2048, 256, 0, stream>>>(out);

    band_patch<<<NTOK / 256, 256, 0, stream>>>(band, sm, out);
}